// Round 1
// 2833.836 us; speedup vs baseline: 1.4951x; 1.4951x over previous
//
#include <hip/hip_runtime.h>

// OR_LSTM Round 9: COLUMN-SPLIT + MFMA rewrite.
// B=32,T=128,D=16,H=256,WS=8,OUT=8. 127 global iterations, 8-slot window pipeline.
// Grid = 256 wgs = 8 slots x 32 col-groups (each owns 8 hidden units = 32 gate
// cols for ALL 32 batch rows). Weight slices are LDS-RESIDENT (~100KB f16
// hi/lo) -> zero per-iteration weight streaming (was 3.14MB/CU/iter from L2,
// the old structural bound). GEMMs via v_mfma_f32_16x16x32_f16 with hi/lo
// split-f16 (2-3 products) for ~fp32 precision, fp32 accumulators.
// Cross-wg per iteration (per slot): all-gather h0' (32KB fp32) after L0 and
// h1 (16KB f16) after L1 through MALL (sc0/sc1 ops + relaxed agent flags,
// the R6-proven primitives). Out-column feedback: single monotonic ncols
// counter, finisher slot's cw0 wg writes column + posts.

#define NWG 256
#define TPB 512

typedef float f32x4 __attribute__((ext_vector_type(4)));
typedef _Float16 f16x8 __attribute__((ext_vector_type(8)));

// ---- workspace byte layout (total 3,133,440 <= proven-safe 3.21MB) ----
#define CTRL_BYTES 36864
#define OFF_W0H   36864      // f16 [1024 cols][296]  (k: 0..15 x | 16..31 zero | 32..287 h0 | pad)
#define OFF_W1AH  643072     // f16 [1024][256] Wih1 hi
#define OFF_W1AL  1167360    // f16 [1024][256] Wih1 lo
#define OFF_W1BH  1691648    // f16 [1024][256] Whh1 hi
#define OFF_W1BL  2215936    // f16 [1024][256] Whh1 lo
#define OFF_H0X   2740224    // f32 [8 slots][32 rows][256 units]
#define OFF_H1X   3002368    // f16 [8 slots][32 rows][256 units]

// ---- ctrl u32 indices (64B-spaced flags) ----
#define NCOLS_U 0
#define F0_U(sl, cw) ((1 + (sl) * 32 + (cw)) * 16)
#define F1_U(sl, cw) ((260 + (sl) * 32 + (cw)) * 16)

// ---- dynamic LDS byte layout (154,144 B <= 160KB) ----
#define L_W0H   0        // f16 [32][296]
#define L_W1AH  18944    // f16 [32][264]
#define L_W1AL  35840
#define L_W1BH  52736
#define L_W1BL  69632
#define L_ABH   86528    // f16 [32 rows][296]: x(0..15)|zeros(16..31)|h0(32..287)
#define L_ABL   105472
#define L_H1H   124416   // f16 [32][264]
#define L_GATES 141312   // f32 [32][33]
#define L_WLIN  145536   // f32 [8][260]
#define L_B0    153856   // f32 [32]
#define L_B1    153984   // f32 [32]
#define L_BLIN  154112   // f32 [8]
#define SMEM_BYTES 154144

__device__ __forceinline__ float sigf(float x) { return 1.0f / (1.0f + __expf(-x)); }
__device__ __forceinline__ float tanhfast(float x) {
  float e = __expf(2.0f * x);
  return 1.0f - 2.0f / (e + 1.0f);
}

__device__ __forceinline__ unsigned rload(const unsigned* p) {
  return __hip_atomic_load(p, __ATOMIC_RELAXED, __HIP_MEMORY_SCOPE_AGENT);
}
__device__ __forceinline__ void rstore(unsigned* p, unsigned v) {
  __hip_atomic_store(p, v, __ATOMIC_RELAXED, __HIP_MEMORY_SCOPE_AGENT);
}
__device__ __forceinline__ float mall_load_f(const float* p) {
  float v;
  asm volatile("global_load_dword %0, %1, off sc0 sc1\n\ts_waitcnt vmcnt(0)"
               : "=v"(v) : "v"(p) : "memory");
  return v;
}
__device__ __forceinline__ void mall_store_f(float* p, float v) {
  asm volatile("global_store_dword %0, %1, off sc0 sc1" :: "v"(p), "v"(v) : "memory");
}
__device__ __forceinline__ void mall_store_u16(unsigned short* p, unsigned short v) {
  unsigned vv = v;
  asm volatile("global_store_short %0, %1, off sc0 sc1" :: "v"(p), "v"(vv) : "memory");
}
__device__ __forceinline__ void mall_load2x4(const float* p, f32x4& a, f32x4& b) {
  asm volatile(
      "global_load_dwordx4 %0, %2, off sc0 sc1\n\t"
      "global_load_dwordx4 %1, %2, off offset:16 sc0 sc1\n\t"
      "s_waitcnt vmcnt(0)"
      : "=&v"(a), "=&v"(b) : "v"(p) : "memory");
}
__device__ __forceinline__ void mall_load4x4(const float* p, f32x4& a, f32x4& b,
                                             f32x4& c, f32x4& d) {
  asm volatile(
      "global_load_dwordx4 %0, %4, off sc0 sc1\n\t"
      "global_load_dwordx4 %1, %4, off offset:16 sc0 sc1\n\t"
      "global_load_dwordx4 %2, %4, off offset:32 sc0 sc1\n\t"
      "global_load_dwordx4 %3, %4, off offset:48 sc0 sc1\n\t"
      "s_waitcnt vmcnt(0)"
      : "=&v"(a), "=&v"(b), "=&v"(c), "=&v"(d) : "v"(p) : "memory");
}
__device__ __forceinline__ void vmdrain() {
  asm volatile("s_waitcnt vmcnt(0)" ::: "memory");
}
__device__ __forceinline__ f32x4 mfma16(f16x8 a, f16x8 b, f32x4 c) {
  return __builtin_amdgcn_mfma_f32_16x16x32_f16(a, b, c, 0, 0, 0);
}
__device__ __forceinline__ void split8(const f32x4 p, const f32x4 q, f16x8& h, f16x8& l) {
  float v[8] = {p.x, p.y, p.z, p.w, q.x, q.y, q.z, q.w};
#pragma unroll
  for (int j = 0; j < 8; ++j) {
    const _Float16 hh = (_Float16)v[j];
    h[j] = hh;
    l[j] = (_Float16)(v[j] - (float)hh);
  }
}

// ---- prep: pack weights into frag-ready f16 planes ----
// col-group cw owns units [cw*8, cw*8+8); local col c = gate*8 + j maps to
// global gate-row J = gate*256 + cw*8 + j.
__global__ __launch_bounds__(256) void lstm_prep(
    const float* __restrict__ Wih0, const float* __restrict__ Whh0,
    const float* __restrict__ Wih1, const float* __restrict__ Whh1,
    char* __restrict__ wsb) {
  const int i = blockIdx.x * 256 + threadIdx.x;
  _Float16* W0H = (_Float16*)(wsb + OFF_W0H);
  _Float16* W1AH = (_Float16*)(wsb + OFF_W1AH);
  _Float16* W1AL = (_Float16*)(wsb + OFF_W1AL);
  _Float16* W1BH = (_Float16*)(wsb + OFF_W1BH);
  _Float16* W1BL = (_Float16*)(wsb + OFF_W1BL);
  if (i < 1024 * 296) {           // W0 hi-only (k-range err ~1e-4/gate, OK)
    const int cg = i / 296, k = i - cg * 296;
    const int cw = cg >> 5, c = cg & 31;
    const int J = (c >> 3) * 256 + cw * 8 + (c & 7);
    float w = 0.f;
    if (k < 16) w = Wih0[J * 16 + k];
    else if (k >= 32 && k < 288) w = Whh0[J * 256 + (k - 32)];
    W0H[i] = (_Float16)w;
  }
  if (i < 1024 * 256) {           // W1A/W1B hi+lo
    const int cg = i >> 8, k = i & 255;
    const int cw = cg >> 5, c = cg & 31;
    const int J = (c >> 3) * 256 + cw * 8 + (c & 7);
    const float wa = Wih1[J * 256 + k];
    _Float16 h = (_Float16)wa;
    W1AH[i] = h; W1AL[i] = (_Float16)(wa - (float)h);
    const float wb = Whh1[J * 256 + k];
    h = (_Float16)wb;
    W1BH[i] = h; W1BL[i] = (_Float16)(wb - (float)h);
  }
}

__global__ __launch_bounds__(TPB, 2) void lstm_main(
    const float* __restrict__ traj,
    const float* __restrict__ bih0, const float* __restrict__ bhh0,
    const float* __restrict__ bih1, const float* __restrict__ bhh1,
    const float* __restrict__ Wlin, const float* __restrict__ blin,
    float* __restrict__ out, char* __restrict__ wsb) {
  extern __shared__ char smem[];
  _Float16* const W0H_  = (_Float16*)(smem + L_W0H);
  _Float16* const W1AH_ = (_Float16*)(smem + L_W1AH);
  _Float16* const W1AL_ = (_Float16*)(smem + L_W1AL);
  _Float16* const W1BH_ = (_Float16*)(smem + L_W1BH);
  _Float16* const W1BL_ = (_Float16*)(smem + L_W1BL);
  _Float16* const ABH_  = (_Float16*)(smem + L_ABH);
  _Float16* const ABL_  = (_Float16*)(smem + L_ABL);
  _Float16* const H1H_  = (_Float16*)(smem + L_H1H);
  float* const GATES_ = (float*)(smem + L_GATES);
  float* const WLIN_  = (float*)(smem + L_WLIN);
  float* const B0_    = (float*)(smem + L_B0);
  float* const B1_    = (float*)(smem + L_B1);
  float* const BLIN_  = (float*)(smem + L_BLIN);

  const int tid = threadIdx.x;
  const int wg = blockIdx.x;
  const int sl = wg & 7;           // pipeline slot (windows t: t%8 == sl)
  const int cw = wg >> 3;          // col-group: units [cw*8, cw*8+8)
  unsigned* ctrl = (unsigned*)wsb;

  // ---- one-time LDS init ----
  {
    const uint* s0 = (const uint*)(wsb + OFF_W0H) + cw * 4736;
    uint* d0 = (uint*)W0H_;
    for (int i = tid; i < 4736; i += TPB) d0[i] = s0[i];
    const uint* s1 = (const uint*)(wsb + OFF_W1AH) + cw * 4096;
    const uint* s2 = (const uint*)(wsb + OFF_W1AL) + cw * 4096;
    const uint* s3 = (const uint*)(wsb + OFF_W1BH) + cw * 4096;
    const uint* s4 = (const uint*)(wsb + OFF_W1BL) + cw * 4096;
    uint* d1 = (uint*)W1AH_; uint* d2 = (uint*)W1AL_;
    uint* d3 = (uint*)W1BH_; uint* d4 = (uint*)W1BL_;
    for (int i = tid; i < 4096; i += TPB) {
      const int c = i >> 7, d = i & 127;  // restride 128 -> 132 dwords
      d1[c * 132 + d] = s1[i];
      d2[c * 132 + d] = s2[i];
      d3[c * 132 + d] = s3[i];
      d4[c * 132 + d] = s4[i];
    }
    for (int i = tid; i < 2048; i += TPB)
      WLIN_[(i >> 8) * 260 + (i & 255)] = Wlin[i];
    if (tid < 32) {
      const int J = (tid >> 3) * 256 + cw * 8 + (tid & 7);
      B0_[tid] = bih0[J] + bhh0[J];
      B1_[tid] = bih1[J] + bhh1[J];
    }
    if (tid < 8) BLIN_[tid] = blin[tid];
    {  // permanent zero block k=16..31 of AB (x-pad; gather never touches it)
      const int r = tid >> 4, kk = 16 + (tid & 15);
      ABH_[r * 296 + kk] = (_Float16)0.f;
      ABL_[r * 296 + kk] = (_Float16)0.f;
    }
  }
  __syncthreads();

  const int rA = tid >> 3, uA = tid & 7;  // activation/head mapping (tid<256)
  unsigned n0 = 0, n1 = 0;
  float c0s = 0.f, c1s = 0.f;             // cell states for (rA, uA)

  for (int g = 0; g < 127; ++g) {
    const int s = (g - sl) & 7;
    const int t = g - s;
    if (t < 0 || t > 119) continue;
    const bool fresh = (s == 0);
    const bool need_fb = (g >= 8);

    // ---- P0: out-column gate ----
    if (need_fb && tid == 0) {
      const unsigned need = (unsigned)(g - 7);
      while (rload(&ctrl[NCOLS_U]) < need) __builtin_amdgcn_s_sleep(1);
    }
    __syncthreads();

    // ---- P1: stage x (split hi/lo into AB[r][0..15]) ----
    {
      const int r = tid >> 4, d = tid & 15;
      float xv;
      if (t <= 7 && s < 8 - t) {
        xv = traj[r * 2048 + (t + s) * 16 + d];
      } else if (d < 8) {
        const int ti = (t <= 7) ? (2 * t + s - 1) : (t + s);
        xv = traj[r * 2048 + ti * 16 + d];
      } else {
        xv = mall_load_f(out + r * 960 + (g - 8) * 8 + (d - 8));
      }
      const _Float16 xh = (_Float16)xv;
      ABH_[r * 296 + d] = xh;
      ABL_[r * 296 + d] = (_Float16)(xv - (float)xh);
    }
    __syncthreads();

    // ---- P2: layer-0 MFMA: gates = [x|0|h0] @ W0 + b0 ----
    if (tid < 256) {
      const int l = tid & 63, wv = tid >> 6;
      const int row = (wv >> 1) * 16 + (l & 15);
      const int col = (wv & 1) * 16 + (l & 15);
      const int kg = (l >> 4) * 8;
      const float bv = B0_[col];
      f32x4 acc = {bv, bv, bv, bv};
      const int nks = fresh ? 1 : 9;  // fresh window: h0=0, only the x k-step
      for (int ks = 0; ks < nks; ++ks) {
        const f16x8 ah = *(const f16x8*)(ABH_ + row * 296 + ks * 32 + kg);
        const f16x8 al = *(const f16x8*)(ABL_ + row * 296 + ks * 32 + kg);
        const f16x8 wh = *(const f16x8*)(W0H_ + col * 296 + ks * 32 + kg);
        acc = mfma16(ah, wh, acc);
        acc = mfma16(al, wh, acc);
      }
      const int gr = (wv >> 1) * 16 + (l >> 4) * 4;
#pragma unroll
      for (int q = 0; q < 4; ++q) GATES_[(gr + q) * 33 + col] = acc[q];
    }
    __syncthreads();

    // ---- P3: LSTM update L0, publish own h0' slice ----
    if (tid < 256) {
      const float iv = GATES_[rA * 33 + uA];
      const float fv = GATES_[rA * 33 + 8 + uA];
      const float gv = GATES_[rA * 33 + 16 + uA];
      const float ov = GATES_[rA * 33 + 24 + uA];
      const float cold = fresh ? 0.f : c0s;
      const float cn = sigf(fv) * cold + sigf(iv) * tanhfast(gv);
      c0s = cn;
      const float hv = sigf(ov) * tanhfast(cn);
      mall_store_f((float*)(wsb + OFF_H0X) + sl * 8192 + rA * 256 + cw * 8 + uA, hv);
      if (g == 126) {  // window 119 epilogue (only slot 7 active here)
        out[30720 + rA * 256 + cw * 8 + uA] = hv;   // h_n L0
        out[47104 + rA * 256 + cw * 8 + uA] = cn;   // c_n L0
      }
    }
    vmdrain();
    __syncthreads();
    ++n0;
    if (tid == 0) rstore(&ctrl[F0_U(sl, cw)], n0);
    __syncthreads();
    if (tid < 32) {
      while (rload(&ctrl[F0_U(sl, tid)]) < n0) __builtin_amdgcn_s_sleep(1);
    }
    __syncthreads();

    // ---- P4: all-gather h0' -> split hi/lo into AB[r][32..287] ----
    {
      const int r = tid >> 4, ch = tid & 15;
      const float* src = (const float*)(wsb + OFF_H0X) + sl * 8192 + r * 256 + ch * 16;
      f32x4 va, vb, vc, vd;
      mall_load4x4(src, va, vb, vc, vd);
      f16x8 h0, l0, h1, l1;
      split8(va, vb, h0, l0);
      split8(vc, vd, h1, l1);
      _Float16* pH = ABH_ + r * 296 + 32 + ch * 16;
      _Float16* pL = ABL_ + r * 296 + 32 + ch * 16;
      *(f16x8*)pH = h0; *(f16x8*)(pH + 8) = h1;
      *(f16x8*)pL = l0; *(f16x8*)(pL + 8) = l1;
    }
    __syncthreads();

    // ---- P5: layer-1 MFMA: gates = h0' @ W1A (3-prod) + h1 @ W1B (2-prod) + b1 ----
    if (tid < 256) {
      const int l = tid & 63, wv = tid >> 6;
      const int row = (wv >> 1) * 16 + (l & 15);
      const int col = (wv & 1) * 16 + (l & 15);
      const int kg = (l >> 4) * 8;
      const float bv = B1_[col];
      f32x4 acc = {bv, bv, bv, bv};
      for (int ks = 0; ks < 8; ++ks) {
        const f16x8 ah = *(const f16x8*)(ABH_ + row * 296 + 32 + ks * 32 + kg);
        const f16x8 al = *(const f16x8*)(ABL_ + row * 296 + 32 + ks * 32 + kg);
        const f16x8 wh = *(const f16x8*)(W1AH_ + col * 264 + ks * 32 + kg);
        const f16x8 wl = *(const f16x8*)(W1AL_ + col * 264 + ks * 32 + kg);
        acc = mfma16(ah, wh, acc);
        acc = mfma16(al, wh, acc);
        acc = mfma16(ah, wl, acc);
      }
      if (!fresh) {
        for (int ks = 0; ks < 8; ++ks) {
          const f16x8 hh = *(const f16x8*)(H1H_ + row * 264 + ks * 32 + kg);
          const f16x8 wh = *(const f16x8*)(W1BH_ + col * 264 + ks * 32 + kg);
          const f16x8 wl = *(const f16x8*)(W1BL_ + col * 264 + ks * 32 + kg);
          acc = mfma16(hh, wh, acc);
          acc = mfma16(hh, wl, acc);
        }
      }
      const int gr = (wv >> 1) * 16 + (l >> 4) * 4;
#pragma unroll
      for (int q = 0; q < 4; ++q) GATES_[(gr + q) * 33 + col] = acc[q];
    }
    __syncthreads();

    // ---- P6: LSTM update L1, publish own h1 slice (f16) ----
    if (tid < 256) {
      const float iv = GATES_[rA * 33 + uA];
      const float fv = GATES_[rA * 33 + 8 + uA];
      const float gv = GATES_[rA * 33 + 16 + uA];
      const float ov = GATES_[rA * 33 + 24 + uA];
      const float cold = fresh ? 0.f : c1s;
      const float cn = sigf(fv) * cold + sigf(iv) * tanhfast(gv);
      c1s = cn;
      const float hv = sigf(ov) * tanhfast(cn);
      union { _Float16 h; unsigned short u; } cv; cv.h = (_Float16)hv;
      mall_store_u16((unsigned short*)(wsb + OFF_H1X) + sl * 8192 + rA * 256 + cw * 8 + uA, cv.u);
      if (g == 126) {
        out[38912 + rA * 256 + cw * 8 + uA] = hv;   // h_n L1
        out[55296 + rA * 256 + cw * 8 + uA] = cn;   // c_n L1
      }
    }
    vmdrain();
    __syncthreads();
    ++n1;
    if (tid == 0) rstore(&ctrl[F1_U(sl, cw)], n1);
    __syncthreads();
    if (tid < 32) {
      while (rload(&ctrl[F1_U(sl, tid)]) < n1) __builtin_amdgcn_s_sleep(1);
    }
    __syncthreads();

    // ---- P7: all-gather h1 (f16 passthrough) into H1 ----
    {
      const int r = tid >> 4, ch = tid & 15;
      const float* src = (const float*)(wsb + OFF_H1X) + sl * 4096 + r * 128 + ch * 8;
      f32x4 va, vb;
      mall_load2x4(src, va, vb);
      *(f32x4*)(H1H_ + r * 264 + ch * 16) = va;
      *(f32x4*)(H1H_ + r * 264 + ch * 16 + 8) = vb;
    }
    __syncthreads();

    // ---- P8: head + out column + ncols (finishing slot, cw==0 only) ----
    if (s == 7 && cw == 0) {
      if (tid < 256) {
        float pred = BLIN_[uA];
        for (int cb = 0; cb < 32; ++cb) {
          const f16x8 hv8 = *(const f16x8*)(H1H_ + rA * 264 + cb * 8);
          const float* wp = WLIN_ + uA * 260 + cb * 8;
#pragma unroll
          for (int j = 0; j < 8; ++j) pred += (float)hv8[j] * wp[j];
        }
        const float base = (t == 0) ? traj[rA * 2048 + 7 * 16 + 8 + uA]
                                    : mall_load_f(out + rA * 960 + (t - 1) * 8 + uA);
        mall_store_f(out + rA * 960 + t * 8 + uA, base + pred);
      }
      vmdrain();
      __syncthreads();
      if (tid == 0) rstore(&ctrl[NCOLS_U], (unsigned)(t + 1));
    }
  }
}

extern "C" void kernel_launch(void* const* d_in, const int* in_sizes, int n_in,
                              void* d_out, int out_size, void* d_ws, size_t ws_size,
                              hipStream_t stream) {
  (void)in_sizes; (void)n_in; (void)out_size; (void)ws_size;
  const float* traj = (const float*)d_in[0];
  const float* Wih0 = (const float*)d_in[1];
  const float* Whh0 = (const float*)d_in[2];
  const float* bih0 = (const float*)d_in[3];
  const float* bhh0 = (const float*)d_in[4];
  const float* Wih1 = (const float*)d_in[5];
  const float* Whh1 = (const float*)d_in[6];
  const float* bih1 = (const float*)d_in[7];
  const float* bhh1 = (const float*)d_in[8];
  const float* Wlin = (const float*)d_in[9];
  const float* blin = (const float*)d_in[10];
  float* out = (float*)d_out;
  char* wsb = (char*)d_ws;

  static bool attr_done = false;
  if (!attr_done) {
    (void)hipFuncSetAttribute((const void*)lstm_main,
                              hipFuncAttributeMaxDynamicSharedMemorySize,
                              SMEM_BYTES);
    attr_done = true;
  }

  hipMemsetAsync(d_ws, 0, CTRL_BYTES, stream);
  lstm_prep<<<1184, 256, 0, stream>>>(Wih0, Whh0, Wih1, Whh1, wsb);

  void* args[] = {(void*)&traj, (void*)&bih0, (void*)&bhh0, (void*)&bih1,
                  (void*)&bhh1, (void*)&Wlin, (void*)&blin, (void*)&out,
                  (void*)&wsb};
  hipLaunchCooperativeKernel((void*)lstm_main, dim3(NWG), dim3(TPB), args,
                             SMEM_BYTES, stream);
}

// Round 2
// 1415.087 us; speedup vs baseline: 2.9940x; 2.0026x over previous
//
#include <hip/hip_runtime.h>

// OR_LSTM Round 10: column-split MFMA + SHORTENED CRITICAL CHAIN.
// B=32,T=128,D=16,H=256,WS=8,OUT=8. 127 iterations, 8-slot window pipeline,
// 256 wgs = 8 slots x 32 col-groups (8 hidden units each), TPB=256.
// R9 was latency-bound (22us/iter, MfmaUtil 1.5%, VALU 2.9%): the whole
// MFMA+exchange chain sat serialized behind the once-per-iteration column.
// R10: (a) L0 h0-part (16 mfma) runs BEFORE the column poll; (b) W1B*h1
// (16 mfma) runs between F0-post and F0-poll (hidden under flag latency);
// (c) head partials computed per-wg from register-fresh f32 h1, finisher
// reduces 32x8 contiguous floats -> h1 state gather moves OFF the critical
// path (after NCOLS post; skipped for the finishing slot); (d) finisher
// base cached in LDS from the staging fetch (kills one MALL RT);
// (e) TPB 256 (4 waves): halves barrier cost. Exchange buffers overlay the
// dead post-init weight regions of ws (init grid-barrier guards), so the ws
// footprint stays at the R8/R9-proven 3.13MB.

#define NWG 256
#define TPB 256

typedef float f32x4 __attribute__((ext_vector_type(4)));
typedef _Float16 f16x8 __attribute__((ext_vector_type(8)));

// ---- workspace byte layout ----
#define CTRL_BYTES 36864
#define OFF_W0H   36864      // f16 [1024 cols][296]   (init-only source)
#define OFF_W1AH  643072     // f16 [1024][256]        (init-only source)
#define OFF_W1AL  1167360
#define OFF_W1BH  1691648
#define OFF_W1BL  2215936
// overlays -- live only AFTER the init grid barrier:
#define OFF_H0X   OFF_W1AH   // u32 [8 sl][8192]  packed {hi16,lo16} h0'
#define OFF_H1X   OFF_W1AL   // u16 [2 parity][8 sl][8192]  f16 h1
#define OFF_PB    OFF_W1BH   // f32 [256 (r*8+o)][32 cw] head partials

// ---- ctrl u32 indices (64B-spaced) ----
#define NCOLS_U 0
#define F0_U(sl, cw) ((1 + (sl) * 32 + (cw)) * 16)
#define F1_U(sl, cw) ((260 + (sl) * 32 + (cw)) * 16)
#define IB_U (520 * 16)

// ---- dynamic LDS byte layout (156,320 <= 160KB) ----
#define L_W0H   0        // f16 [32][296]
#define L_W1AH  18944    // f16 [32][264]
#define L_W1AL  35840
#define L_W1BH  52736
#define L_W1BL  69632
#define L_ABH   86528    // f16 [32 rows][296]: x(0..15)|zero(16..31)|h0(32..287)
#define L_ABL   105472
#define L_H1H   124416   // f16 [32][264]
#define L_GATES 141312   // f32 [32][33]
#define L_WLIN  145536   // f32 [8][260]
#define L_HOWN  153856   // f32 [32][9]  own h1 slice (for head partials)
#define L_BASE  155008   // f32 [32][8]  cached out[:,g-8] (finisher base)
#define L_B0    156032   // f32 [32]
#define L_B1    156160   // f32 [32]
#define L_BLIN  156288   // f32 [8]
#define SMEM_BYTES 156320

__device__ __forceinline__ float sigf(float x) { return 1.0f / (1.0f + __expf(-x)); }
__device__ __forceinline__ float tanhfast(float x) {
  float e = __expf(2.0f * x);
  return 1.0f - 2.0f / (e + 1.0f);
}
__device__ __forceinline__ unsigned f16u(_Float16 h) {
  union { _Float16 h; unsigned short u; } c; c.h = h; return c.u;
}
__device__ __forceinline__ unsigned fbits(float x) {
  union { float f; unsigned u; } c; c.f = x; return c.u;
}

__device__ __forceinline__ unsigned rload(const unsigned* p) {
  return __hip_atomic_load(p, __ATOMIC_RELAXED, __HIP_MEMORY_SCOPE_AGENT);
}
__device__ __forceinline__ void rstore(unsigned* p, unsigned v) {
  __hip_atomic_store(p, v, __ATOMIC_RELAXED, __HIP_MEMORY_SCOPE_AGENT);
}
__device__ __forceinline__ float mall_load_f(const float* p) {
  float v;
  asm volatile("global_load_dword %0, %1, off sc0 sc1\n\ts_waitcnt vmcnt(0)"
               : "=v"(v) : "v"(p) : "memory");
  return v;
}
__device__ __forceinline__ void mall_store_f(float* p, float v) {
  asm volatile("global_store_dword %0, %1, off sc0 sc1" :: "v"(p), "v"(v) : "memory");
}
__device__ __forceinline__ void mall_store_u32(unsigned* p, unsigned v) {
  asm volatile("global_store_dword %0, %1, off sc0 sc1" :: "v"(p), "v"(v) : "memory");
}
__device__ __forceinline__ void mall_store_u16(unsigned short* p, unsigned v) {
  asm volatile("global_store_short %0, %1, off sc0 sc1" :: "v"(p), "v"(v) : "memory");
}
__device__ __forceinline__ void mall_load4x4(const float* p, f32x4& a, f32x4& b,
                                             f32x4& c, f32x4& d) {
  asm volatile(
      "global_load_dwordx4 %0, %4, off sc0 sc1\n\t"
      "global_load_dwordx4 %1, %4, off offset:16 sc0 sc1\n\t"
      "global_load_dwordx4 %2, %4, off offset:32 sc0 sc1\n\t"
      "global_load_dwordx4 %3, %4, off offset:48 sc0 sc1\n\t"
      "s_waitcnt vmcnt(0)"
      : "=&v"(a), "=&v"(b), "=&v"(c), "=&v"(d) : "v"(p) : "memory");
}
__device__ __forceinline__ void mall_load8x4(const void* p, f32x4& a0, f32x4& a1,
                                             f32x4& a2, f32x4& a3, f32x4& a4,
                                             f32x4& a5, f32x4& a6, f32x4& a7) {
  asm volatile(
      "global_load_dwordx4 %0, %8, off sc0 sc1\n\t"
      "global_load_dwordx4 %1, %8, off offset:16 sc0 sc1\n\t"
      "global_load_dwordx4 %2, %8, off offset:32 sc0 sc1\n\t"
      "global_load_dwordx4 %3, %8, off offset:48 sc0 sc1\n\t"
      "global_load_dwordx4 %4, %8, off offset:64 sc0 sc1\n\t"
      "global_load_dwordx4 %5, %8, off offset:80 sc0 sc1\n\t"
      "global_load_dwordx4 %6, %8, off offset:96 sc0 sc1\n\t"
      "global_load_dwordx4 %7, %8, off offset:112 sc0 sc1\n\t"
      "s_waitcnt vmcnt(0)"
      : "=&v"(a0), "=&v"(a1), "=&v"(a2), "=&v"(a3),
        "=&v"(a4), "=&v"(a5), "=&v"(a6), "=&v"(a7)
      : "v"(p) : "memory");
}
__device__ __forceinline__ void vmdrain() {
  asm volatile("s_waitcnt vmcnt(0)" ::: "memory");
}
__device__ __forceinline__ f32x4 mfma16(f16x8 a, f16x8 b, f32x4 c) {
  return __builtin_amdgcn_mfma_f32_16x16x32_f16(a, b, c, 0, 0, 0);
}

// ---- prep (unchanged from R9): pack weights into frag-ready f16 planes ----
__global__ __launch_bounds__(256) void lstm_prep(
    const float* __restrict__ Wih0, const float* __restrict__ Whh0,
    const float* __restrict__ Wih1, const float* __restrict__ Whh1,
    char* __restrict__ wsb) {
  const int i = blockIdx.x * 256 + threadIdx.x;
  _Float16* W0H = (_Float16*)(wsb + OFF_W0H);
  _Float16* W1AH = (_Float16*)(wsb + OFF_W1AH);
  _Float16* W1AL = (_Float16*)(wsb + OFF_W1AL);
  _Float16* W1BH = (_Float16*)(wsb + OFF_W1BH);
  _Float16* W1BL = (_Float16*)(wsb + OFF_W1BL);
  if (i < 1024 * 296) {           // W0 hi-only
    const int cg = i / 296, k = i - cg * 296;
    const int cw = cg >> 5, c = cg & 31;
    const int J = (c >> 3) * 256 + cw * 8 + (c & 7);
    float w = 0.f;
    if (k < 16) w = Wih0[J * 16 + k];
    else if (k >= 32 && k < 288) w = Whh0[J * 256 + (k - 32)];
    W0H[i] = (_Float16)w;
  }
  if (i < 1024 * 256) {           // W1A/W1B hi+lo
    const int cg = i >> 8, k = i & 255;
    const int cw = cg >> 5, c = cg & 31;
    const int J = (c >> 3) * 256 + cw * 8 + (c & 7);
    const float wa = Wih1[J * 256 + k];
    _Float16 h = (_Float16)wa;
    W1AH[i] = h; W1AL[i] = (_Float16)(wa - (float)h);
    const float wb = Whh1[J * 256 + k];
    h = (_Float16)wb;
    W1BH[i] = h; W1BL[i] = (_Float16)(wb - (float)h);
  }
}

#define UNPK(vv, i2) {                                              \
    const unsigned w0 = fbits(vv.x), w1 = fbits(vv.y);              \
    const unsigned w2 = fbits(vv.z), w3 = fbits(vv.w);              \
    ah32[(i2)]     = (w0 & 0xffffu) | (w1 << 16);                   \
    ah32[(i2) + 1] = (w2 & 0xffffu) | (w3 << 16);                   \
    al32[(i2)]     = (w0 >> 16) | (w1 & 0xffff0000u);               \
    al32[(i2) + 1] = (w2 >> 16) | (w3 & 0xffff0000u); }

__global__ __launch_bounds__(TPB, 1) void lstm_main(
    const float* __restrict__ traj,
    const float* __restrict__ bih0, const float* __restrict__ bhh0,
    const float* __restrict__ bih1, const float* __restrict__ bhh1,
    const float* __restrict__ Wlin, const float* __restrict__ blin,
    float* __restrict__ out, char* __restrict__ wsb) {
  extern __shared__ char smem[];
  _Float16* const W0H_  = (_Float16*)(smem + L_W0H);
  _Float16* const W1AH_ = (_Float16*)(smem + L_W1AH);
  _Float16* const W1AL_ = (_Float16*)(smem + L_W1AL);
  _Float16* const W1BH_ = (_Float16*)(smem + L_W1BH);
  _Float16* const W1BL_ = (_Float16*)(smem + L_W1BL);
  _Float16* const ABH_  = (_Float16*)(smem + L_ABH);
  _Float16* const ABL_  = (_Float16*)(smem + L_ABL);
  _Float16* const H1H_  = (_Float16*)(smem + L_H1H);
  float* const GATES_ = (float*)(smem + L_GATES);
  float* const WLIN_  = (float*)(smem + L_WLIN);
  float* const HOWN_  = (float*)(smem + L_HOWN);
  float* const BASE_  = (float*)(smem + L_BASE);
  float* const B0_    = (float*)(smem + L_B0);
  float* const B1_    = (float*)(smem + L_B1);
  float* const BLIN_  = (float*)(smem + L_BLIN);

  const int tid = threadIdx.x;
  const int wg = blockIdx.x;
  const int sl = wg & 7;           // pipeline slot (windows t: t%8 == sl)
  const int cw = wg >> 3;          // col-group: units [cw*8, cw*8+8)
  unsigned* ctrl = (unsigned*)wsb;

  // ---- one-time LDS init from packed ws ----
  {
    const unsigned* s0 = (const unsigned*)(wsb + OFF_W0H) + cw * 4736;
    unsigned* d0 = (unsigned*)W0H_;
    for (int i = tid; i < 4736; i += TPB) d0[i] = s0[i];
    const unsigned* s1 = (const unsigned*)(wsb + OFF_W1AH) + cw * 4096;
    const unsigned* s2 = (const unsigned*)(wsb + OFF_W1AL) + cw * 4096;
    const unsigned* s3 = (const unsigned*)(wsb + OFF_W1BH) + cw * 4096;
    const unsigned* s4 = (const unsigned*)(wsb + OFF_W1BL) + cw * 4096;
    unsigned* d1 = (unsigned*)W1AH_; unsigned* d2 = (unsigned*)W1AL_;
    unsigned* d3 = (unsigned*)W1BH_; unsigned* d4 = (unsigned*)W1BL_;
    for (int i = tid; i < 4096; i += TPB) {
      const int c = i >> 7, d = i & 127;  // restride 128 -> 132 dwords
      d1[c * 132 + d] = s1[i];
      d2[c * 132 + d] = s2[i];
      d3[c * 132 + d] = s3[i];
      d4[c * 132 + d] = s4[i];
    }
    for (int i = tid; i < 2048; i += TPB)
      WLIN_[(i >> 8) * 260 + (i & 255)] = Wlin[i];
    if (tid < 32) {
      const int J = (tid >> 3) * 256 + cw * 8 + (tid & 7);
      B0_[tid] = bih0[J] + bhh0[J];
      B1_[tid] = bih1[J] + bhh1[J];
    }
    if (tid < 8) BLIN_[tid] = blin[tid];
    {  // permanent zero pad k=16..31 of AB (never overwritten)
      const int r = tid >> 3, q = tid & 7;
      ((unsigned*)ABH_)[r * 148 + 8 + q] = 0u;
      ((unsigned*)ABL_)[r * 148 + 8 + q] = 0u;
    }
  }
  __syncthreads();
  // init grid barrier: ws weight regions become overlay buffers after this
  if (tid == 0) {
    __hip_atomic_fetch_add(&ctrl[IB_U], 1u, __ATOMIC_RELAXED,
                           __HIP_MEMORY_SCOPE_AGENT);
    while (rload(&ctrl[IB_U]) < NWG) __builtin_amdgcn_s_sleep(1);
  }
  __syncthreads();

  // per-thread constants
  const int l = tid & 63, wv = tid >> 6;
  const int frow = ((wv >> 1) << 4) + (l & 15);   // A-frag row (batch)
  const int fcol = ((wv & 1) << 4) + (l & 15);    // B-frag col (local gate col)
  const int kg = (l >> 4) << 3;                   // k sub-offset within K=32
  const int gr = ((wv >> 1) << 4) + ((l >> 4) << 2);  // C-frag row base
  const int rA = tid >> 3, uA = tid & 7;          // activation mapping

  unsigned n0 = 0, n1 = 0;
  float c0s = 0.f, c1s = 0.f;

  for (int g = 0; g < 127; ++g) {
    const int s = (g - sl) & 7;
    const int t = g - s;
    if (t < 0 || t > 119) continue;
    const bool fresh = (s == 0);

    // ---- A: L0 h0-part (pre-column; h0 gathered last iteration) ----
    f32x4 acc0;
    { const float b = B0_[fcol]; acc0 = (f32x4){b, b, b, b}; }
    if (!fresh) {
      for (int ks = 0; ks < 8; ++ks) {
        const f16x8 ah = *(const f16x8*)(ABH_ + frow * 296 + 32 + ks * 32 + kg);
        const f16x8 al = *(const f16x8*)(ABL_ + frow * 296 + 32 + ks * 32 + kg);
        const f16x8 wh = *(const f16x8*)(W0H_ + fcol * 296 + 32 + ks * 32 + kg);
        acc0 = mfma16(ah, wh, acc0);
        acc0 = mfma16(al, wh, acc0);
      }
    }

    // ---- C: column gate (the ONLY cross-slot dependency) ----
    if (g >= 8 && tid == 0) {
      const unsigned need = (unsigned)(g - 7);
      while (rload(&ctrl[NCOLS_U]) < need) __builtin_amdgcn_s_sleep(1);
    }
    __syncthreads();

    // ---- D: stage x -> AB[0..15] (hi/lo packed u32 writes) ----
    {
      const int r = tid >> 3, dp = (tid & 7) << 1;
      float x0, x1;
      if (t <= 7 && s < 8 - t) {
        const float* tp = traj + r * 2048 + (t + s) * 16 + dp;
        x0 = tp[0]; x1 = tp[1];
      } else if (dp < 8) {
        const int ti = (t <= 7) ? (2 * t + s - 1) : (t + s);
        const float* tp = traj + r * 2048 + ti * 16 + dp;
        x0 = tp[0]; x1 = tp[1];
      } else {
        const float* cp = out + r * 960 + (g - 8) * 8 + (dp - 8);
        x0 = mall_load_f(cp);
        x1 = mall_load_f(cp + 1);
        if (s == 7) {  // cache: this IS the finisher's base out[:,t-1]
          BASE_[r * 8 + dp - 8] = x0;
          BASE_[r * 8 + dp - 7] = x1;
        }
      }
      const _Float16 h0 = (_Float16)x0, h1v = (_Float16)x1;
      const unsigned hw = f16u(h0) | (f16u(h1v) << 16);
      const unsigned lw = f16u((_Float16)(x0 - (float)h0)) |
                          (f16u((_Float16)(x1 - (float)h1v)) << 16);
      ((unsigned*)ABH_)[r * 148 + (dp >> 1)] = hw;
      ((unsigned*)ABL_)[r * 148 + (dp >> 1)] = lw;
    }
    __syncthreads();

    // ---- E: L0 x k-step, gates out ----
    {
      const f16x8 ah = *(const f16x8*)(ABH_ + frow * 296 + kg);
      const f16x8 al = *(const f16x8*)(ABL_ + frow * 296 + kg);
      const f16x8 wh = *(const f16x8*)(W0H_ + fcol * 296 + kg);
      acc0 = mfma16(ah, wh, acc0);
      acc0 = mfma16(al, wh, acc0);
#pragma unroll
      for (int q = 0; q < 4; ++q) GATES_[(gr + q) * 33 + fcol] = acc0[q];
    }
    __syncthreads();

    // ---- F: L0 act + publish own h0' slice (packed {hi,lo} u32) ----
    {
      const float iv = GATES_[rA * 33 + uA];
      const float fv = GATES_[rA * 33 + 8 + uA];
      const float gv = GATES_[rA * 33 + 16 + uA];
      const float ov = GATES_[rA * 33 + 24 + uA];
      const float cold = fresh ? 0.f : c0s;
      const float cn = sigf(fv) * cold + sigf(iv) * tanhfast(gv);
      c0s = cn;
      const float hv = sigf(ov) * tanhfast(cn);
      const _Float16 hh = (_Float16)hv;
      const unsigned w = f16u(hh) | (f16u((_Float16)(hv - (float)hh)) << 16);
      mall_store_u32((unsigned*)(wsb + OFF_H0X) + sl * 8192 + rA * 256 + cw * 8 + uA, w);
      if (g == 126) {
        out[30720 + rA * 256 + cw * 8 + uA] = hv;   // h_n L0
        out[47104 + rA * 256 + cw * 8 + uA] = cn;   // c_n L0
      }
    }
    vmdrain();
    __syncthreads();
    ++n0;
    if (tid == 0) rstore(&ctrl[F0_U(sl, cw)], n0);

    // ---- B': W1B*h1 (hidden under F0 flag propagation) ----
    f32x4 acc1;
    { const float b = B1_[fcol]; acc1 = (f32x4){b, b, b, b}; }
    if (!fresh) {
      for (int ks = 0; ks < 8; ++ks) {
        const f16x8 hh = *(const f16x8*)(H1H_ + frow * 264 + ks * 32 + kg);
        const f16x8 wh = *(const f16x8*)(W1BH_ + fcol * 264 + ks * 32 + kg);
        const f16x8 wl = *(const f16x8*)(W1BL_ + fcol * 264 + ks * 32 + kg);
        acc1 = mfma16(hh, wh, acc1);
        acc1 = mfma16(hh, wl, acc1);
      }
    }

    // ---- G: F0 poll ----
    if (tid < 32) {
      while (rload(&ctrl[F0_U(sl, tid)]) < n0) __builtin_amdgcn_s_sleep(1);
    }
    __syncthreads();

    // ---- H: gather h0' (32KB packed) -> unpack into AB[32..287] ----
    {
      const int r = tid >> 3, c32 = (tid & 7) << 5;
      const unsigned* src = (const unsigned*)(wsb + OFF_H0X) + sl * 8192 + r * 256 + c32;
      f32x4 v0, v1, v2, v3, v4, v5, v6, v7;
      mall_load8x4(src, v0, v1, v2, v3, v4, v5, v6, v7);
      unsigned* ah32 = (unsigned*)ABH_ + r * 148 + 16 + (c32 >> 1);
      unsigned* al32 = (unsigned*)ABL_ + r * 148 + 16 + (c32 >> 1);
      UNPK(v0, 0)  UNPK(v1, 2)  UNPK(v2, 4)  UNPK(v3, 6)
      UNPK(v4, 8)  UNPK(v5, 10) UNPK(v6, 12) UNPK(v7, 14)
    }
    __syncthreads();

    // ---- I: L1 W1A part (3 products), gates out ----
    {
      for (int ks = 0; ks < 8; ++ks) {
        const f16x8 ah = *(const f16x8*)(ABH_ + frow * 296 + 32 + ks * 32 + kg);
        const f16x8 al = *(const f16x8*)(ABL_ + frow * 296 + 32 + ks * 32 + kg);
        const f16x8 wh = *(const f16x8*)(W1AH_ + fcol * 264 + ks * 32 + kg);
        const f16x8 wl = *(const f16x8*)(W1AL_ + fcol * 264 + ks * 32 + kg);
        acc1 = mfma16(ah, wh, acc1);
        acc1 = mfma16(al, wh, acc1);
        acc1 = mfma16(ah, wl, acc1);
      }
#pragma unroll
      for (int q = 0; q < 4; ++q) GATES_[(gr + q) * 33 + fcol] = acc1[q];
    }
    __syncthreads();

    // ---- J: L1 act; publish h1 (s<7) / head partials (s==7) ----
    {
      const float iv = GATES_[rA * 33 + uA];
      const float fv = GATES_[rA * 33 + 8 + uA];
      const float gv = GATES_[rA * 33 + 16 + uA];
      const float ov = GATES_[rA * 33 + 24 + uA];
      const float cold = fresh ? 0.f : c1s;
      const float cn = sigf(fv) * cold + sigf(iv) * tanhfast(gv);
      c1s = cn;
      const float hv = sigf(ov) * tanhfast(cn);
      HOWN_[rA * 9 + uA] = hv;
      if (s < 7) {
        mall_store_u16((unsigned short*)(wsb + OFF_H1X) + (g & 1) * 65536 +
                           sl * 8192 + rA * 256 + cw * 8 + uA,
                       f16u((_Float16)hv));
      }
      if (g == 126) {
        out[38912 + rA * 256 + cw * 8 + uA] = hv;   // h_n L1
        out[55296 + rA * 256 + cw * 8 + uA] = cn;   // c_n L1
      }
    }
    __syncthreads();
    if (s == 7) {  // head partials from f32-fresh own h1 (better than R9 f16)
      const int o = tid & 7;
      const float* wl = WLIN_ + o * 260 + cw * 8;
      const float* hb = HOWN_ + (tid >> 3) * 9;
      float p = 0.f;
#pragma unroll
      for (int u = 0; u < 8; ++u) p = fmaf(hb[u], wl[u], p);
      mall_store_f((float*)(wsb + OFF_PB) + tid * 32 + cw, p);
    }
    vmdrain();
    __syncthreads();
    ++n1;
    if (tid == 0) rstore(&ctrl[F1_U(sl, cw)], n1);

    // ---- K: F1 poll ----
    if (tid < 32) {
      while (rload(&ctrl[F1_U(sl, tid)]) < n1) __builtin_amdgcn_s_sleep(1);
    }
    __syncthreads();

    // ---- L: finisher -> column + NCOLS; others -> h1 state gather ----
    if (s == 7) {
      if (cw == 0) {
        const int r = tid >> 3, o = tid & 7;
        f32x4 p0, p1, p2, p3, p4, p5, p6, p7;
        mall_load8x4((const float*)(wsb + OFF_PB) + tid * 32,
                     p0, p1, p2, p3, p4, p5, p6, p7);
        float pred = BLIN_[o]
            + p0.x + p0.y + p0.z + p0.w + p1.x + p1.y + p1.z + p1.w
            + p2.x + p2.y + p2.z + p2.w + p3.x + p3.y + p3.z + p3.w
            + p4.x + p4.y + p4.z + p4.w + p5.x + p5.y + p5.z + p5.w
            + p6.x + p6.y + p6.z + p6.w + p7.x + p7.y + p7.z + p7.w;
        const float base = (t == 0) ? traj[r * 2048 + 7 * 16 + 8 + o]
                                    : BASE_[tid];
        mall_store_f(out + r * 960 + t * 8 + o, base + pred);
        vmdrain();
        __syncthreads();
        if (tid == 0) rstore(&ctrl[NCOLS_U], (unsigned)(t + 1));
      }
      // finishing slot's next window is fresh: no h1 state needed
    } else {
      const int r = tid >> 3, c = tid & 7;
      const char* src = wsb + OFF_H1X + (g & 1) * 131072 + sl * 16384 +
                        r * 512 + c * 64;
      f32x4 a, b, c4, d;
      mall_load4x4((const float*)src, a, b, c4, d);
      f32x4* dst = (f32x4*)(H1H_ + r * 264 + c * 32);
      dst[0] = a; dst[1] = b; dst[2] = c4; dst[3] = d;
    }
    __syncthreads();
  }
}

extern "C" void kernel_launch(void* const* d_in, const int* in_sizes, int n_in,
                              void* d_out, int out_size, void* d_ws, size_t ws_size,
                              hipStream_t stream) {
  (void)in_sizes; (void)n_in; (void)out_size; (void)ws_size;
  const float* traj = (const float*)d_in[0];
  const float* Wih0 = (const float*)d_in[1];
  const float* Whh0 = (const float*)d_in[2];
  const float* bih0 = (const float*)d_in[3];
  const float* bhh0 = (const float*)d_in[4];
  const float* Wih1 = (const float*)d_in[5];
  const float* Whh1 = (const float*)d_in[6];
  const float* bih1 = (const float*)d_in[7];
  const float* bhh1 = (const float*)d_in[8];
  const float* Wlin = (const float*)d_in[9];
  const float* blin = (const float*)d_in[10];
  float* out = (float*)d_out;
  char* wsb = (char*)d_ws;

  static bool attr_done = false;
  if (!attr_done) {
    (void)hipFuncSetAttribute((const void*)lstm_main,
                              hipFuncAttributeMaxDynamicSharedMemorySize,
                              SMEM_BYTES);
    attr_done = true;
  }

  hipMemsetAsync(d_ws, 0, CTRL_BYTES, stream);
  lstm_prep<<<1184, 256, 0, stream>>>(Wih0, Whh0, Wih1, Whh1, wsb);

  void* args[] = {(void*)&traj, (void*)&bih0, (void*)&bhh0, (void*)&bih1,
                  (void*)&bhh1, (void*)&Wlin, (void*)&blin, (void*)&out,
                  (void*)&wsb};
  hipLaunchCooperativeKernel((void*)lstm_main, dim3(NWG), dim3(TPB), args,
                             SMEM_BYTES, stream);
}

// Round 3
// 1236.617 us; speedup vs baseline: 3.4261x; 1.1443x over previous
//
#include <hip/hip_runtime.h>

// OR_LSTM Round 11: TAG-IN-DATA exchange protocol (flag-free).
// B=32,T=128,D=16,H=256,WS=8,OUT=8. 127 iterations, 8-slot window pipeline,
// 256 wgs = 8 slots x 32 col-groups (8 hidden units each), TPB=256.
// R10 was protocol-latency-bound (10.6us/iter, MfmaUtil 3.3%): each exchange
// cost store->drain->flag->poll->load (~3 MALL RTs) x3 per iteration.
// R11: tags ride IN the exchanged words (bit0="written", bit1=(g>>1)&1 stolen
// from f16-lo / f32 mantissa; g&1 double-buffer separates g/g-1; tag bit1
// separates g/g-2; zero-init separates first use). Producer just stores;
// consumer polls the data itself -- the poll IS the gather (~1.5 RT).
// Column feedback via tagged colX mirror (f16 hi/lo packed, frag-ready);
// head partials via tagged f32 PB. All flags, NCOLS, and in-loop vmdrains
// are gone; 6 barriers/iter (was ~11).

#define NWG 256
#define TPB 256

typedef float f32x4 __attribute__((ext_vector_type(4)));
typedef _Float16 f16x8 __attribute__((ext_vector_type(8)));
typedef unsigned u32x2 __attribute__((ext_vector_type(2)));

// ---- workspace byte layout ----
#define CTRL_BYTES 4096
#define OFF_W0H   36864      // f16 [1024 cols][296]   (init-only source)
#define OFF_W1AH  643072     // f16 [1024][256]        (init-only source)
#define OFF_W1AL  1167360
#define OFF_W1BH  1691648
#define OFF_W1BL  2215936
// overlays (live after init grid barriers; zeroed in-kernel between them):
#define OFF_H0X   OFF_W1AH   // u32 [2 par][8 sl][32 r][256 u] {hi16,lo16+tag}
#define OFF_H1X   OFF_W1AL   // u32 [2 par][8 sl][32 r][256 u] {hi16,lo16+tag}
#define ZERO_BYTES 1048576   // h0X + h1X
// never-written-by-prep region (zeroed by memsetAsync):
#define OFF_COLX  2740224    // u32 [120 t][32 r][8 o]  {hi16, lo16|bit0}
#define OFF_PB    2863104    // f32 [2 par][256 (r*8+o)][32 cw]  bits1:0=tag
#define PBCOLX_BYTES 188416  // 122880 + 65536

// ---- ctrl u32 indices ----
#define IB1_U 16
#define IB2_U 32

// ---- dynamic LDS byte layout (identical to R10; 156,320 <= 160KB) ----
#define L_W0H   0        // f16 [32][296]
#define L_W1AH  18944    // f16 [32][264]
#define L_W1AL  35840
#define L_W1BH  52736
#define L_W1BL  69632
#define L_ABH   86528    // f16 [32 rows][296]: x(0..15)|zero(16..31)|h0(32..287)
#define L_ABL   105472
#define L_H1H   124416   // f16 [32][264]
#define L_GATES 141312   // f32 [32][33]
#define L_WLIN  145536   // f32 [8][260]
#define L_HOWN  153856   // f32 [32][9]
#define L_BASE  155008   // f32 [32][8]
#define L_B0    156032
#define L_B1    156160
#define L_BLIN  156288
#define SMEM_BYTES 156320

__device__ __forceinline__ float sigf(float x) { return 1.0f / (1.0f + __expf(-x)); }
__device__ __forceinline__ float tanhfast(float x) {
  float e = __expf(2.0f * x);
  return 1.0f - 2.0f / (e + 1.0f);
}
__device__ __forceinline__ unsigned f16u(_Float16 h) {
  union { _Float16 h; unsigned short u; } c; c.h = h; return c.u;
}
__device__ __forceinline__ float uf16(unsigned u) {
  union { unsigned short s; _Float16 h; } c; c.s = (unsigned short)u; return (float)c.h;
}
__device__ __forceinline__ unsigned fbits(float x) {
  union { float f; unsigned u; } c; c.f = x; return c.u;
}
__device__ __forceinline__ void splitpack(float x0, float x1, unsigned& hw, unsigned& lw) {
  const _Float16 a = (_Float16)x0, b = (_Float16)x1;
  hw = f16u(a) | (f16u(b) << 16);
  lw = f16u((_Float16)(x0 - (float)a)) | (f16u((_Float16)(x1 - (float)b)) << 16);
}

__device__ __forceinline__ unsigned rload(const unsigned* p) {
  return __hip_atomic_load(p, __ATOMIC_RELAXED, __HIP_MEMORY_SCOPE_AGENT);
}
__device__ __forceinline__ void mall_store_u32(unsigned* p, unsigned v) {
  asm volatile("global_store_dword %0, %1, off sc0 sc1" :: "v"(p), "v"(v) : "memory");
}
__device__ __forceinline__ void mall_load8x4(const void* p, f32x4& a0, f32x4& a1,
                                             f32x4& a2, f32x4& a3, f32x4& a4,
                                             f32x4& a5, f32x4& a6, f32x4& a7) {
  asm volatile(
      "global_load_dwordx4 %0, %8, off sc0 sc1\n\t"
      "global_load_dwordx4 %1, %8, off offset:16 sc0 sc1\n\t"
      "global_load_dwordx4 %2, %8, off offset:32 sc0 sc1\n\t"
      "global_load_dwordx4 %3, %8, off offset:48 sc0 sc1\n\t"
      "global_load_dwordx4 %4, %8, off offset:64 sc0 sc1\n\t"
      "global_load_dwordx4 %5, %8, off offset:80 sc0 sc1\n\t"
      "global_load_dwordx4 %6, %8, off offset:96 sc0 sc1\n\t"
      "global_load_dwordx4 %7, %8, off offset:112 sc0 sc1\n\t"
      "s_waitcnt vmcnt(0)"
      : "=&v"(a0), "=&v"(a1), "=&v"(a2), "=&v"(a3),
        "=&v"(a4), "=&v"(a5), "=&v"(a6), "=&v"(a7)
      : "v"(p) : "memory");
}
__device__ __forceinline__ void mall_load2(const void* p, unsigned& x, unsigned& y) {
  u32x2 v;
  asm volatile("global_load_dwordx2 %0, %1, off sc0 sc1\n\ts_waitcnt vmcnt(0)"
               : "=v"(v) : "v"(p) : "memory");
  x = v.x; y = v.y;
}
__device__ __forceinline__ void vmdrain() {
  asm volatile("s_waitcnt vmcnt(0)" ::: "memory");
}
__device__ __forceinline__ f32x4 mfma16(f16x8 a, f16x8 b, f32x4 c) {
  return __builtin_amdgcn_mfma_f32_16x16x32_f16(a, b, c, 0, 0, 0);
}

// tag checks: h0X/h1X words carry tag in bits 17:16; PB f32 in bits 1:0.
#define TG4(vv) (((fbits(vv.x) >> 16) & 3u) == tagv) & (((fbits(vv.y) >> 16) & 3u) == tagv) & \
                (((fbits(vv.z) >> 16) & 3u) == tagv) & (((fbits(vv.w) >> 16) & 3u) == tagv)
#define TP4(vv) ((fbits(vv.x) & 3u) == tagv) & ((fbits(vv.y) & 3u) == tagv) & \
                ((fbits(vv.z) & 3u) == tagv) & ((fbits(vv.w) & 3u) == tagv)
#define UNPK(vv, i2) {                                              \
    const unsigned w0 = fbits(vv.x), w1 = fbits(vv.y);              \
    const unsigned w2 = fbits(vv.z), w3 = fbits(vv.w);              \
    ah32[(i2)]     = (w0 & 0xffffu) | (w1 << 16);                   \
    ah32[(i2) + 1] = (w2 & 0xffffu) | (w3 << 16);                   \
    al32[(i2)]     = (w0 >> 16) | (w1 & 0xffff0000u);               \
    al32[(i2) + 1] = (w2 >> 16) | (w3 & 0xffff0000u); }
#define PKH(vv, i2) {                                               \
    dst[(i2)]     = (fbits(vv.x) & 0xffffu) | ((fbits(vv.y) & 0xffffu) << 16); \
    dst[(i2) + 1] = (fbits(vv.z) & 0xffffu) | ((fbits(vv.w) & 0xffffu) << 16); }

// ---- prep (unchanged): pack weights into frag-ready f16 planes ----
__global__ __launch_bounds__(256) void lstm_prep(
    const float* __restrict__ Wih0, const float* __restrict__ Whh0,
    const float* __restrict__ Wih1, const float* __restrict__ Whh1,
    char* __restrict__ wsb) {
  const int i = blockIdx.x * 256 + threadIdx.x;
  _Float16* W0H = (_Float16*)(wsb + OFF_W0H);
  _Float16* W1AH = (_Float16*)(wsb + OFF_W1AH);
  _Float16* W1AL = (_Float16*)(wsb + OFF_W1AL);
  _Float16* W1BH = (_Float16*)(wsb + OFF_W1BH);
  _Float16* W1BL = (_Float16*)(wsb + OFF_W1BL);
  if (i < 1024 * 296) {           // W0 hi-only
    const int cg = i / 296, k = i - cg * 296;
    const int cw = cg >> 5, c = cg & 31;
    const int J = (c >> 3) * 256 + cw * 8 + (c & 7);
    float w = 0.f;
    if (k < 16) w = Wih0[J * 16 + k];
    else if (k >= 32 && k < 288) w = Whh0[J * 256 + (k - 32)];
    W0H[i] = (_Float16)w;
  }
  if (i < 1024 * 256) {           // W1A/W1B hi+lo
    const int cg = i >> 8, k = i & 255;
    const int cw = cg >> 5, c = cg & 31;
    const int J = (c >> 3) * 256 + cw * 8 + (c & 7);
    const float wa = Wih1[J * 256 + k];
    _Float16 h = (_Float16)wa;
    W1AH[i] = h; W1AL[i] = (_Float16)(wa - (float)h);
    const float wb = Whh1[J * 256 + k];
    h = (_Float16)wb;
    W1BH[i] = h; W1BL[i] = (_Float16)(wb - (float)h);
  }
}

__global__ __launch_bounds__(TPB, 1) void lstm_main(
    const float* __restrict__ traj,
    const float* __restrict__ bih0, const float* __restrict__ bhh0,
    const float* __restrict__ bih1, const float* __restrict__ bhh1,
    const float* __restrict__ Wlin, const float* __restrict__ blin,
    float* __restrict__ out, char* __restrict__ wsb) {
  extern __shared__ char smem[];
  _Float16* const W0H_  = (_Float16*)(smem + L_W0H);
  _Float16* const W1AH_ = (_Float16*)(smem + L_W1AH);
  _Float16* const W1AL_ = (_Float16*)(smem + L_W1AL);
  _Float16* const W1BH_ = (_Float16*)(smem + L_W1BH);
  _Float16* const W1BL_ = (_Float16*)(smem + L_W1BL);
  _Float16* const ABH_  = (_Float16*)(smem + L_ABH);
  _Float16* const ABL_  = (_Float16*)(smem + L_ABL);
  _Float16* const H1H_  = (_Float16*)(smem + L_H1H);
  float* const GATES_ = (float*)(smem + L_GATES);
  float* const WLIN_  = (float*)(smem + L_WLIN);
  float* const HOWN_  = (float*)(smem + L_HOWN);
  float* const BASE_  = (float*)(smem + L_BASE);
  float* const B0_    = (float*)(smem + L_B0);
  float* const B1_    = (float*)(smem + L_B1);
  float* const BLIN_  = (float*)(smem + L_BLIN);

  const int tid = threadIdx.x;
  const int wg = blockIdx.x;
  const int sl = wg & 7;           // pipeline slot
  const int cw = wg >> 3;          // col-group: units [cw*8, cw*8+8)
  unsigned* ctrl = (unsigned*)wsb;
  unsigned* const h0x = (unsigned*)(wsb + OFF_H0X);
  unsigned* const h1x = (unsigned*)(wsb + OFF_H1X);
  unsigned* const colx = (unsigned*)(wsb + OFF_COLX);
  float* const pb = (float*)(wsb + OFF_PB);

  // ---- one-time LDS init from packed ws ----
  {
    const unsigned* s0 = (const unsigned*)(wsb + OFF_W0H) + cw * 4736;
    unsigned* d0 = (unsigned*)W0H_;
    for (int i = tid; i < 4736; i += TPB) d0[i] = s0[i];
    const unsigned* s1 = (const unsigned*)(wsb + OFF_W1AH) + cw * 4096;
    const unsigned* s2 = (const unsigned*)(wsb + OFF_W1AL) + cw * 4096;
    const unsigned* s3 = (const unsigned*)(wsb + OFF_W1BH) + cw * 4096;
    const unsigned* s4 = (const unsigned*)(wsb + OFF_W1BL) + cw * 4096;
    unsigned* d1 = (unsigned*)W1AH_; unsigned* d2 = (unsigned*)W1AL_;
    unsigned* d3 = (unsigned*)W1BH_; unsigned* d4 = (unsigned*)W1BL_;
    for (int i = tid; i < 4096; i += TPB) {
      const int c = i >> 7, d = i & 127;  // restride 128 -> 132 dwords
      d1[c * 132 + d] = s1[i];
      d2[c * 132 + d] = s2[i];
      d3[c * 132 + d] = s3[i];
      d4[c * 132 + d] = s4[i];
    }
    for (int i = tid; i < 2048; i += TPB)
      WLIN_[(i >> 8) * 260 + (i & 255)] = Wlin[i];
    if (tid < 32) {
      const int J = (tid >> 3) * 256 + cw * 8 + (tid & 7);
      B0_[tid] = bih0[J] + bhh0[J];
      B1_[tid] = bih1[J] + bhh1[J];
    }
    if (tid < 8) BLIN_[tid] = blin[tid];
    {  // permanent zero pad k=16..31 of AB
      const int r = tid >> 3, q = tid & 7;
      ((unsigned*)ABH_)[r * 148 + 8 + q] = 0u;
      ((unsigned*)ABL_)[r * 148 + 8 + q] = 0u;
    }
  }
  // grid barrier 1: everyone done READING overlay weight regions
  __syncthreads();
  if (tid == 0) {
    __hip_atomic_fetch_add(&ctrl[IB1_U], 1u, __ATOMIC_RELAXED,
                           __HIP_MEMORY_SCOPE_AGENT);
    while (rload(&ctrl[IB1_U]) < NWG) __builtin_amdgcn_s_sleep(1);
  }
  __syncthreads();
  // zero tagged-exchange overlays (h0X+h1X, 1MB; 4KB per wg) via MALL stores
  {
    unsigned* z = (unsigned*)(wsb + OFF_H0X) + wg * 1024;
#pragma unroll
    for (int i = 0; i < 4; ++i) mall_store_u32(z + i * TPB + tid, 0u);
    vmdrain();
  }
  // grid barrier 2: zeroing visible everywhere
  __syncthreads();
  if (tid == 0) {
    __hip_atomic_fetch_add(&ctrl[IB2_U], 1u, __ATOMIC_RELAXED,
                           __HIP_MEMORY_SCOPE_AGENT);
    while (rload(&ctrl[IB2_U]) < NWG) __builtin_amdgcn_s_sleep(1);
  }
  __syncthreads();

  // per-thread constants
  const int l = tid & 63, wv = tid >> 6;
  const int frow = ((wv >> 1) << 4) + (l & 15);
  const int fcol = ((wv & 1) << 4) + (l & 15);
  const int kg = (l >> 4) << 3;
  const int gr = ((wv >> 1) << 4) + ((l >> 4) << 2);
  const int rA = tid >> 3, uA = tid & 7;

  float c0s = 0.f, c1s = 0.f;

  for (int g = 0; g < 127; ++g) {
    const int s = (g - sl) & 7;
    const int t = g - s;
    if (t < 0 || t > 119) continue;
    const bool fresh = (s == 0);
    const int gb = g & 1;                            // buffer parity
    const unsigned tagv = 1u | (((unsigned)(g >> 1) & 1u) << 1);  // {bit1,bit0}

    // ---- A: L0 h0-part (pre-feedback; AB h0 gathered last iteration) ----
    f32x4 acc0;
    { const float b = B0_[fcol]; acc0 = (f32x4){b, b, b, b}; }
    if (!fresh) {
      for (int ks = 0; ks < 8; ++ks) {
        const f16x8 ah = *(const f16x8*)(ABH_ + frow * 296 + 32 + ks * 32 + kg);
        const f16x8 al = *(const f16x8*)(ABL_ + frow * 296 + 32 + ks * 32 + kg);
        const f16x8 wh = *(const f16x8*)(W0H_ + fcol * 296 + 32 + ks * 32 + kg);
        acc0 = mfma16(ah, wh, acc0);
        acc0 = mfma16(al, wh, acc0);
      }
    }

    // ---- D: stage x -> AB[0..15]; feedback dims poll tagged colX ----
    {
      const int r = tid >> 3, dp = (tid & 7) << 1;
      unsigned hw, lw;
      if (t <= 7 && s < 8 - t) {
        const float* tp = traj + r * 2048 + (t + s) * 16 + dp;
        splitpack(tp[0], tp[1], hw, lw);
      } else if (dp < 8) {
        const int ti = (t <= 7) ? (2 * t + s - 1) : (t + s);
        const float* tp = traj + r * 2048 + ti * 16 + dp;
        splitpack(tp[0], tp[1], hw, lw);
      } else {
        const unsigned* cp = colx + (g - 8) * 256 + r * 8 + (dp - 8);
        unsigned w0, w1;
        do { mall_load2(cp, w0, w1); } while (!(w0 & 0x10000u) || !(w1 & 0x10000u));
        hw = (w0 & 0xffffu) | ((w1 & 0xffffu) << 16);
        lw = (w0 >> 16) | (w1 & 0xffff0000u);
        if (s == 7) {  // cache finisher base out[:,t-1] (hi+lo reconstruction)
          BASE_[r * 8 + dp - 8] = uf16(w0 & 0xffffu) + uf16(w0 >> 16);
          BASE_[r * 8 + dp - 7] = uf16(w1 & 0xffffu) + uf16(w1 >> 16);
        }
      }
      ((unsigned*)ABH_)[r * 148 + (dp >> 1)] = hw;
      ((unsigned*)ABL_)[r * 148 + (dp >> 1)] = lw;
    }
    __syncthreads();

    // ---- E: L0 x k-step, gates out ----
    {
      const f16x8 ah = *(const f16x8*)(ABH_ + frow * 296 + kg);
      const f16x8 al = *(const f16x8*)(ABL_ + frow * 296 + kg);
      const f16x8 wh = *(const f16x8*)(W0H_ + fcol * 296 + kg);
      acc0 = mfma16(ah, wh, acc0);
      acc0 = mfma16(al, wh, acc0);
#pragma unroll
      for (int q = 0; q < 4; ++q) GATES_[(gr + q) * 33 + fcol] = acc0[q];
    }
    __syncthreads();

    // ---- F: L0 act + tagged h0X publish (NO drain, NO flag) ----
    {
      const float iv = GATES_[rA * 33 + uA];
      const float fv = GATES_[rA * 33 + 8 + uA];
      const float gv = GATES_[rA * 33 + 16 + uA];
      const float ov = GATES_[rA * 33 + 24 + uA];
      const float cold = fresh ? 0.f : c0s;
      const float cn = sigf(fv) * cold + sigf(iv) * tanhfast(gv);
      c0s = cn;
      const float hv = sigf(ov) * tanhfast(cn);
      const _Float16 hh = (_Float16)hv;
      unsigned lo = f16u((_Float16)(hv - (float)hh));
      lo = (lo & 0xFFFCu) | tagv;
      mall_store_u32(h0x + gb * 65536 + sl * 8192 + rA * 256 + cw * 8 + uA,
                     f16u(hh) | (lo << 16));
      if (g == 126) {
        out[30720 + rA * 256 + cw * 8 + uA] = hv;   // h_n L0
        out[47104 + rA * 256 + cw * 8 + uA] = cn;   // c_n L0
      }
    }

    // ---- B': W1B*h1 (overlaps h0X store flight) ----
    f32x4 acc1;
    { const float b = B1_[fcol]; acc1 = (f32x4){b, b, b, b}; }
    if (!fresh) {
      for (int ks = 0; ks < 8; ++ks) {
        const f16x8 hh = *(const f16x8*)(H1H_ + frow * 264 + ks * 32 + kg);
        const f16x8 wh = *(const f16x8*)(W1BH_ + fcol * 264 + ks * 32 + kg);
        const f16x8 wl = *(const f16x8*)(W1BL_ + fcol * 264 + ks * 32 + kg);
        acc1 = mfma16(hh, wh, acc1);
        acc1 = mfma16(hh, wl, acc1);
      }
    }

    // ---- H: poll-gather tagged h0X -> unpack into AB[32..287] ----
    {
      const int r = tid >> 3, c32 = (tid & 7) << 5;
      const unsigned* src = h0x + gb * 65536 + sl * 8192 + r * 256 + c32;
      f32x4 v0, v1, v2, v3, v4, v5, v6, v7;
      while (true) {
        mall_load8x4(src, v0, v1, v2, v3, v4, v5, v6, v7);
        const unsigned ok = TG4(v0) & TG4(v1) & TG4(v2) & TG4(v3) &
                            TG4(v4) & TG4(v5) & TG4(v6) & TG4(v7);
        if (ok) break;
      }
      unsigned* ah32 = (unsigned*)ABH_ + r * 148 + 16 + (c32 >> 1);
      unsigned* al32 = (unsigned*)ABL_ + r * 148 + 16 + (c32 >> 1);
      UNPK(v0, 0)  UNPK(v1, 2)  UNPK(v2, 4)  UNPK(v3, 6)
      UNPK(v4, 8)  UNPK(v5, 10) UNPK(v6, 12) UNPK(v7, 14)
    }
    __syncthreads();

    // ---- I: L1 W1A part (3 products), gates out ----
    {
      for (int ks = 0; ks < 8; ++ks) {
        const f16x8 ah = *(const f16x8*)(ABH_ + frow * 296 + 32 + ks * 32 + kg);
        const f16x8 al = *(const f16x8*)(ABL_ + frow * 296 + 32 + ks * 32 + kg);
        const f16x8 wh = *(const f16x8*)(W1AH_ + fcol * 264 + ks * 32 + kg);
        const f16x8 wl = *(const f16x8*)(W1AL_ + fcol * 264 + ks * 32 + kg);
        acc1 = mfma16(ah, wh, acc1);
        acc1 = mfma16(al, wh, acc1);
        acc1 = mfma16(ah, wl, acc1);
      }
#pragma unroll
      for (int q = 0; q < 4; ++q) GATES_[(gr + q) * 33 + fcol] = acc1[q];
    }
    __syncthreads();

    // ---- J: L1 act; HOWN; tagged h1X publish (s<7) ----
    {
      const float iv = GATES_[rA * 33 + uA];
      const float fv = GATES_[rA * 33 + 8 + uA];
      const float gv = GATES_[rA * 33 + 16 + uA];
      const float ov = GATES_[rA * 33 + 24 + uA];
      const float cold = fresh ? 0.f : c1s;
      const float cn = sigf(fv) * cold + sigf(iv) * tanhfast(gv);
      c1s = cn;
      const float hv = sigf(ov) * tanhfast(cn);
      HOWN_[rA * 9 + uA] = hv;
      if (s < 7) {
        const _Float16 hh = (_Float16)hv;
        unsigned lo = f16u((_Float16)(hv - (float)hh));
        lo = (lo & 0xFFFCu) | tagv;
        mall_store_u32(h1x + gb * 65536 + sl * 8192 + rA * 256 + cw * 8 + uA,
                       f16u(hh) | (lo << 16));
      }
      if (g == 126) {
        out[38912 + rA * 256 + cw * 8 + uA] = hv;   // h_n L1
        out[55296 + rA * 256 + cw * 8 + uA] = cn;   // c_n L1
      }
    }
    __syncthreads();

    // ---- s==7: head partials (tagged f32 PB) ----
    if (s == 7) {
      const int o = tid & 7;
      const float* wl = WLIN_ + o * 260 + cw * 8;
      const float* hb = HOWN_ + (tid >> 3) * 9;
      float p = 0.f;
#pragma unroll
      for (int u = 0; u < 8; ++u) p = fmaf(hb[u], wl[u], p);
      unsigned pu = (fbits(p) & ~3u) | tagv;
      mall_store_u32((unsigned*)pb + gb * 8192 + tid * 32 + cw, pu);
    }

    // ---- L: finisher -> colX + out; others -> tagged h1X gather ----
    if (s == 7) {
      if (cw == 0) {
        const int r = tid >> 3, o = tid & 7;
        const float* src = pb + gb * 8192 + tid * 32;
        f32x4 p0, p1, p2, p3, p4, p5, p6, p7;
        while (true) {
          mall_load8x4(src, p0, p1, p2, p3, p4, p5, p6, p7);
          const unsigned ok = TP4(p0) & TP4(p1) & TP4(p2) & TP4(p3) &
                              TP4(p4) & TP4(p5) & TP4(p6) & TP4(p7);
          if (ok) break;
        }
        float pred = BLIN_[o]
            + p0.x + p0.y + p0.z + p0.w + p1.x + p1.y + p1.z + p1.w
            + p2.x + p2.y + p2.z + p2.w + p3.x + p3.y + p3.z + p3.w
            + p4.x + p4.y + p4.z + p4.w + p5.x + p5.y + p5.z + p5.w
            + p6.x + p6.y + p6.z + p6.w + p7.x + p7.y + p7.z + p7.w;
        const float base = (t == 0) ? traj[r * 2048 + 7 * 16 + 8 + o]
                                    : BASE_[tid];
        const float v = base + pred;
        out[r * 960 + t * 8 + o] = v;               // exact f32 result
        const _Float16 hh = (_Float16)v;            // tagged mirror for feedback
        unsigned lo = f16u((_Float16)(v - (float)hh));
        lo = (lo & 0xFFFEu) | 1u;
        mall_store_u32(colx + t * 256 + tid, f16u(hh) | (lo << 16));
      }
      // finishing slot's next window is fresh: no h1 gather needed
    } else {
      const int r = tid >> 3, c32 = (tid & 7) << 5;
      const unsigned* src = h1x + gb * 65536 + sl * 8192 + r * 256 + c32;
      f32x4 v0, v1, v2, v3, v4, v5, v6, v7;
      while (true) {
        mall_load8x4(src, v0, v1, v2, v3, v4, v5, v6, v7);
        const unsigned ok = TG4(v0) & TG4(v1) & TG4(v2) & TG4(v3) &
                            TG4(v4) & TG4(v5) & TG4(v6) & TG4(v7);
        if (ok) break;
      }
      unsigned* dst = (unsigned*)H1H_ + r * 132 + (c32 >> 1);
      PKH(v0, 0)  PKH(v1, 2)  PKH(v2, 4)  PKH(v3, 6)
      PKH(v4, 8)  PKH(v5, 10) PKH(v6, 12) PKH(v7, 14)
    }
    __syncthreads();
  }
}

extern "C" void kernel_launch(void* const* d_in, const int* in_sizes, int n_in,
                              void* d_out, int out_size, void* d_ws, size_t ws_size,
                              hipStream_t stream) {
  (void)in_sizes; (void)n_in; (void)out_size; (void)ws_size;
  const float* traj = (const float*)d_in[0];
  const float* Wih0 = (const float*)d_in[1];
  const float* Whh0 = (const float*)d_in[2];
  const float* bih0 = (const float*)d_in[3];
  const float* bhh0 = (const float*)d_in[4];
  const float* Wih1 = (const float*)d_in[5];
  const float* Whh1 = (const float*)d_in[6];
  const float* bih1 = (const float*)d_in[7];
  const float* bhh1 = (const float*)d_in[8];
  const float* Wlin = (const float*)d_in[9];
  const float* blin = (const float*)d_in[10];
  float* out = (float*)d_out;
  char* wsb = (char*)d_ws;

  static bool attr_done = false;
  if (!attr_done) {
    (void)hipFuncSetAttribute((const void*)lstm_main,
                              hipFuncAttributeMaxDynamicSharedMemorySize,
                              SMEM_BYTES);
    attr_done = true;
  }

  hipMemsetAsync(d_ws, 0, CTRL_BYTES, stream);
  hipMemsetAsync(wsb + OFF_COLX, 0, PBCOLX_BYTES, stream);
  lstm_prep<<<1184, 256, 0, stream>>>(Wih0, Whh0, Wih1, Whh1, wsb);

  void* args[] = {(void*)&traj, (void*)&bih0, (void*)&bhh0, (void*)&bih1,
                  (void*)&bhh1, (void*)&Wlin, (void*)&blin, (void*)&out,
                  (void*)&wsb};
  hipLaunchCooperativeKernel((void*)lstm_main, dim3(NWG), dim3(TPB), args,
                             SMEM_BYTES, stream);
}